// Round 3
// baseline (4696.365 us; speedup 1.0000x reference)
//
#include <hip/hip_runtime.h>

// CPCGNN: LSTM(2048 x 128 steps, F=16, H=256) -> GATv2 x2 (16-node graphs) ->
// mean pool -> CPC loss. Inputs/outputs FLOAT32; MFMA paths use bf16 copies.
//
// Round 3: LSTM rebuilt as 512 WGs (4 per 16-row tile), W_hh register-resident
// (128 VGPRs/lane, loaded once), per-step h-slice exchange through L2 with
// agent-scope release/acquire flags. XCD-colocated blockIdx swizzle.

typedef __bf16 bf16;
typedef bf16 bf16x4 __attribute__((ext_vector_type(4)));
typedef bf16 bf16x8 __attribute__((ext_vector_type(8)));
typedef float f32x4 __attribute__((ext_vector_type(4)));

__device__ __forceinline__ float fast_sigmoid(float x) {
    return __builtin_amdgcn_rcpf(1.0f + __expf(-x));
}
__device__ __forceinline__ float fast_tanh(float x) {
    return 2.0f * __builtin_amdgcn_rcpf(1.0f + __expf(-2.0f * x)) - 1.0f;
}
__device__ __forceinline__ bf16x8 zero8() {
    bf16x8 z;
#pragma unroll
    for (int i = 0; i < 8; ++i) z[i] = (bf16)0.0f;
    return z;
}
__device__ __forceinline__ bf16x8 load8_bf(const float* p) {
    float4 a = *(const float4*)p;
    float4 b = *(const float4*)(p + 4);
    bf16x8 r;
    r[0] = (bf16)a.x; r[1] = (bf16)a.y; r[2] = (bf16)a.z; r[3] = (bf16)a.w;
    r[4] = (bf16)b.x; r[5] = (bf16)b.y; r[6] = (bf16)b.z; r[7] = (bf16)b.w;
    return r;
}

// ---------------------------------------------------------------------------
// 0. Weight f32 -> bf16 conversions + zero the lstm sync flags (512 ints).
// ---------------------------------------------------------------------------
__global__ __launch_bounds__(256, 1) void cvt6(
    const float* __restrict__ s0, const float* __restrict__ s1,
    const float* __restrict__ s2, const float* __restrict__ s3,
    const float* __restrict__ s4, const float* __restrict__ s5,
    bf16* __restrict__ d0, bf16* __restrict__ d1, bf16* __restrict__ d2,
    bf16* __restrict__ d3, bf16* __restrict__ d4, bf16* __restrict__ d5,
    int* __restrict__ flags)
{
    if (blockIdx.x == 0 && threadIdx.x < 512) flags[threadIdx.x] = 0;
    const int n0 = 16384, n1 = 262144, n2 = 524288, n3 = 524288, n4 = 65536;
    int loc = (blockIdx.x * 256 + threadIdx.x) * 4;
    const float* s; bf16* d;
    if (loc < n0)              { s = s0; d = d0; }
    else if ((loc -= n0) < n1) { s = s1; d = d1; }
    else if ((loc -= n1) < n2) { s = s2; d = d2; }
    else if ((loc -= n2) < n3) { s = s3; d = d3; }
    else if ((loc -= n3) < n4) { s = s4; d = d4; }
    else                       { loc -= n4; s = s5; d = d5; }
    float4 v = *(const float4*)(s + loc);
    bf16x4 o;
    o[0] = (bf16)v.x; o[1] = (bf16)v.y; o[2] = (bf16)v.z; o[3] = (bf16)v.w;
    *(bf16x4*)(d + loc) = o;
}

// ---------------------------------------------------------------------------
// 1. LSTM, register-resident W_hh. 512 WGs = 128 row-tiles x 4 members.
//    Member m owns taus [4m,4m+4) (h-cols [64m,64m+64)); wave w -> tau 4m+w,
//    all 4 gates. W_hh B-fragments (32 x bf16x8 = 128 VGPR) loaded once.
//    Per step: 36 MFMA; h slices exchanged via hx (double-buffered, in L2)
//    with agent-scope release/acquire flags. blockIdx swizzled so the 4
//    members of a group land on the same XCD (bid % 8 round-robin).
// ---------------------------------------------------------------------------
__global__ __launch_bounds__(256, 2) void lstm_kernel(
    const float* __restrict__ agent_obs,  // (128,128,16,16) f32
    const bf16* __restrict__ W_ih,        // (1024,16) bf16
    const bf16* __restrict__ W_hh,        // (1024,256) bf16
    const float* __restrict__ b_ih,
    const float* __restrict__ b_hh,
    bf16* __restrict__ hn,                // (2048,256) bf16
    bf16* __restrict__ hx,                // (128,2,16,256) bf16 exchange
    int* __restrict__ flags)              // (128,4)
{
    __shared__ bf16 hbuf[16][264];
    const int tid  = threadIdx.x;
    const int lane = tid & 63;
    const int wv   = tid >> 6;
    const int col  = lane & 15;           // A-row (agent) / B-col (within tau)
    const int grp  = lane >> 4;           // k-group
    // bid = (g&7) + 8*((g>>3)*4 + m)  -> all members of g on one XCD
    const int bid = blockIdx.x;
    const int t   = bid >> 3;
    const int m   = t & 3;
    const int g   = (bid & 7) | ((t >> 2) << 3);   // row-tile / graph id
    const int tau = m * 4 + wv;

    for (int i = tid; i < 16 * 264; i += 256) (&hbuf[0][0])[i] = (bf16)0.0f;

    // per-lane invariants
    float bias[4];
    bf16x8 wih[4];
    bf16x8 wreg[4][8];                    // 128 VGPRs: W_hh resident
#pragma unroll
    for (int G = 0; G < 4; ++G) {
        int n = G * 256 + tau * 16 + col;
        bias[G] = b_ih[n] + b_hh[n];
        wih[G] = (grp < 2) ? *(const bf16x8*)&W_ih[n * 16 + grp * 8] : zero8();
#pragma unroll
        for (int kc = 0; kc < 8; ++kc)
            wreg[G][kc] = *(const bf16x8*)&W_hh[(size_t)n * 256 + kc * 32 + grp * 8];
    }
    f32x4 c = (f32x4){0.0f, 0.0f, 0.0f, 0.0f};

    bf16* hxg = hx + (size_t)g * 8192;    // 2*16*256
    int* flg = flags + g * 4;
    const float* xbase = agent_obs + (size_t)g * 32768;

    __syncthreads();

    for (int s = 0; s < 128; ++s) {
        bf16x8 ax = (grp < 2) ? load8_bf(xbase + s * 256 + col * 16 + grp * 8)
                              : zero8();
        f32x4 acc[4];
#pragma unroll
        for (int G = 0; G < 4; ++G) {
            float bs = bias[G];
            acc[G] = (f32x4){bs, bs, bs, bs};
            acc[G] = __builtin_amdgcn_mfma_f32_16x16x32_bf16(ax, wih[G], acc[G], 0, 0, 0);
        }
#pragma unroll
        for (int kc = 0; kc < 8; ++kc) {
            bf16x8 ah = *(const bf16x8*)&hbuf[col][kc * 32 + grp * 8];
#pragma unroll
            for (int G = 0; G < 4; ++G)
                acc[G] = __builtin_amdgcn_mfma_f32_16x16x32_bf16(ah, wreg[G][kc], acc[G], 0, 0, 0);
        }
        const int p = (s + 1) & 1;
        bf16* hxw = hxg + p * 4096;
#pragma unroll
        for (int r = 0; r < 4; ++r) {
            float iv = fast_sigmoid(acc[0][r]);
            float fv = fast_sigmoid(acc[1][r]);
            float gv = fast_tanh(acc[2][r]);
            float ov = fast_sigmoid(acc[3][r]);
            float cn = fv * c[r] + iv * gv;
            c[r] = cn;
            float hv = ov * fast_tanh(cn);
            int row = grp * 4 + r, cc = tau * 16 + col;
            if (s == 127) hn[((size_t)g * 16 + row) * 256 + cc] = (bf16)hv;
            else          hxw[row * 256 + cc] = (bf16)hv;
        }
        if (s == 127) break;
        __syncthreads();                  // drains stores (vmcnt 0) + LDS reads done
        if (tid == 0) {
            __hip_atomic_store(&flg[m], s + 1, __ATOMIC_RELEASE,
                               __HIP_MEMORY_SCOPE_AGENT);
            int it = 0;
            for (;;) {
                int f0 = __hip_atomic_load(&flg[0], __ATOMIC_ACQUIRE, __HIP_MEMORY_SCOPE_AGENT);
                int f1 = __hip_atomic_load(&flg[1], __ATOMIC_ACQUIRE, __HIP_MEMORY_SCOPE_AGENT);
                int f2 = __hip_atomic_load(&flg[2], __ATOMIC_ACQUIRE, __HIP_MEMORY_SCOPE_AGENT);
                int f3 = __hip_atomic_load(&flg[3], __ATOMIC_ACQUIRE, __HIP_MEMORY_SCOPE_AGENT);
                if (f0 > s && f1 > s && f2 > s && f3 > s) break;
                __builtin_amdgcn_s_sleep(8);
                if (++it > (1 << 22)) break;   // safety valve: no hard hang
            }
        }
        __syncthreads();
        {   // reload full h_{s+1} (16x256) into LDS
            const bf16* hxr = hxg + p * 4096;
            int row = tid >> 4, c0 = (tid & 15) * 16;
            bf16x8 v0 = *(const bf16x8*)(hxr + row * 256 + c0);
            bf16x8 v1 = *(const bf16x8*)(hxr + row * 256 + c0 + 8);
            *(bf16x8*)&hbuf[row][c0] = v0;
            *(bf16x8*)&hbuf[row][c0 + 8] = v1;
        }
        __syncthreads();
    }
}

// ---------------------------------------------------------------------------
// 2. GEMM: C[M,N] = A[M,256] @ W[N,256]^T + bias. A,W,C bf16; bias f32.
// ---------------------------------------------------------------------------
__global__ __launch_bounds__(256, 1) void gemm_bias(
    const bf16* __restrict__ A, const bf16* __restrict__ W,
    const float* __restrict__ bias, bf16* __restrict__ C, int M, int N)
{
    const int tid = threadIdx.x, lane = tid & 63, wv = tid >> 6;
    const int col = lane & 15, grp = lane >> 4;
    const int n = blockIdx.x * 64 + wv * 16 + col;
    const int bm = blockIdx.y * 64;
    float bs = bias[n];
    f32x4 acc[4];
#pragma unroll
    for (int mt = 0; mt < 4; ++mt) acc[mt] = (f32x4){bs, bs, bs, bs};
#pragma unroll
    for (int kc = 0; kc < 8; ++kc) {
        bf16x8 bw = *(const bf16x8*)&W[(size_t)n * 256 + kc * 32 + grp * 8];
#pragma unroll
        for (int mt = 0; mt < 4; ++mt) {
            bf16x8 aa = *(const bf16x8*)
                &A[(size_t)(bm + mt * 16 + col) * 256 + kc * 32 + grp * 8];
            acc[mt] = __builtin_amdgcn_mfma_f32_16x16x32_bf16(aa, bw, acc[mt], 0, 0, 0);
        }
    }
#pragma unroll
    for (int mt = 0; mt < 4; ++mt)
#pragma unroll
        for (int r = 0; r < 4; ++r)
            C[(size_t)(bm + mt * 16 + grp * 4 + r) * N + n] = (bf16)acc[mt][r];
}

// ---------------------------------------------------------------------------
// 3. GATv2 layer 1: scores + edge softmax (no self) + head-mean aggregation.
// ---------------------------------------------------------------------------
__global__ __launch_bounds__(256, 1) void gat1_kernel(
    const bf16* __restrict__ src,    // (2048, 2048) = (b*16+n, h*256+f)
    const bf16* __restrict__ dst,
    const float* __restrict__ attn,  // (8,256) f32
    bf16* __restrict__ r1)           // (2048, 256)
{
    __shared__ float sal[2048];      // (i*16+j)*8+h
    const int tid = threadIdx.x, b = blockIdx.x;
    const bf16* sb = src + (size_t)b * 32768;
    const bf16* db = dst + (size_t)b * 32768;

    for (int ii = 0; ii < 8; ++ii) {
        int trip = tid + ii * 256;            // i*128 + j*8 + h
        int i = trip >> 7, j = (trip >> 3) & 15, h = trip & 7;
        const bf16* ps = sb + j * 2048 + h * 256;
        const bf16* pd = db + i * 2048 + h * 256;
        const float* pa = attn + h * 256;
        float acc = 0.0f;
        for (int f8 = 0; f8 < 32; ++f8) {
            bf16x8 vs = *(const bf16x8*)(ps + f8 * 8);
            bf16x8 vd = *(const bf16x8*)(pd + f8 * 8);
            float4 a0 = *(const float4*)(pa + f8 * 8);
            float4 a1 = *(const float4*)(pa + f8 * 8 + 4);
            float av[8] = {a0.x, a0.y, a0.z, a0.w, a1.x, a1.y, a1.z, a1.w};
#pragma unroll
            for (int e = 0; e < 8; ++e) {
                float v = (float)vs[e] + (float)vd[e];
                v = v > 0.0f ? v : 0.2f * v;
                acc += v * av[e];
            }
        }
        sal[trip] = acc;
    }
    __syncthreads();
    if (tid < 128) {                          // softmax over j != i
        int i = tid >> 3, h = tid & 7;
        float m = -1e30f;
#pragma unroll
        for (int j = 0; j < 16; ++j)
            if (j != i) m = fmaxf(m, sal[(i * 16 + j) * 8 + h]);
        float ex[16], den = 0.0f;
#pragma unroll
        for (int j = 0; j < 16; ++j) {
            ex[j] = (j == i) ? 0.0f : __expf(sal[(i * 16 + j) * 8 + h] - m);
            den += ex[j];
        }
        float rd = 1.0f / den;
#pragma unroll
        for (int j = 0; j < 16; ++j) sal[(i * 16 + j) * 8 + h] = ex[j] * rd;
    }
    __syncthreads();
    {
        int i = tid >> 4, fb = tid & 15;
        for (int it = 0; it < 16; ++it) {
            int f = fb + it * 16;
            float acc = 0.0f;
            for (int j = 0; j < 16; ++j) {
                const bf16* ps = sb + j * 2048 + f;
#pragma unroll
                for (int h = 0; h < 8; ++h)
                    acc += sal[(i * 16 + j) * 8 + h] * (float)ps[h * 256];
            }
            r1[((size_t)b * 16 + i) * 256 + f] = (bf16)(acc * 0.125f);
        }
    }
}

// ---------------------------------------------------------------------------
// 4. GATv2 layer 2 (1 head) fused with node-mean + d_out row writes.
// ---------------------------------------------------------------------------
__global__ __launch_bounds__(256, 1) void gat2_kernel(
    const bf16* __restrict__ src2,   // (2048,256)
    const bf16* __restrict__ dst2,
    const float* __restrict__ attn2, // (256) f32
    const float* __restrict__ hideout,   // (128,2) f32
    const float* __restrict__ timestep,  // (128,1) f32
    float* __restrict__ out,             // (128,259)+loss f32
    float* __restrict__ ac_ws)           // (128,256) f32
{
    __shared__ float sal[256];
    __shared__ float wj[16];
    const int tid = threadIdx.x, b = blockIdx.x;
    const bf16* sb = src2 + (size_t)b * 4096;
    const bf16* db = dst2 + (size_t)b * 4096;
    {
        int i = tid >> 4, j = tid & 15;
        const bf16* ps = sb + j * 256;
        const bf16* pd = db + i * 256;
        float acc = 0.0f;
        for (int g8 = 0; g8 < 32; ++g8) {
            bf16x8 vs = *(const bf16x8*)(ps + g8 * 8);
            bf16x8 vd = *(const bf16x8*)(pd + g8 * 8);
            float4 a0 = *(const float4*)(attn2 + g8 * 8);
            float4 a1 = *(const float4*)(attn2 + g8 * 8 + 4);
            float av[8] = {a0.x, a0.y, a0.z, a0.w, a1.x, a1.y, a1.z, a1.w};
#pragma unroll
            for (int e = 0; e < 8; ++e) {
                float v = (float)vs[e] + (float)vd[e];
                v = v > 0.0f ? v : 0.2f * v;
                acc += v * av[e];
            }
        }
        sal[tid] = acc;
    }
    __syncthreads();
    if (tid < 16) {
        int i = tid;
        float m = -1e30f;
#pragma unroll
        for (int j = 0; j < 16; ++j)
            if (j != i) m = fmaxf(m, sal[i * 16 + j]);
        float ex[16], den = 0.0f;
#pragma unroll
        for (int j = 0; j < 16; ++j) {
            ex[j] = (j == i) ? 0.0f : __expf(sal[i * 16 + j] - m);
            den += ex[j];
        }
        float rd = 1.0f / den;
#pragma unroll
        for (int j = 0; j < 16; ++j) sal[i * 16 + j] = ex[j] * rd;
    }
    __syncthreads();
    if (tid < 16) {
        float a = 0.0f;
#pragma unroll
        for (int i = 0; i < 16; ++i) a += sal[i * 16 + tid];
        wj[tid] = a * (1.0f / 16.0f);
    }
    __syncthreads();
    {
        int g = tid;
        float acc = 0.0f;
#pragma unroll
        for (int j = 0; j < 16; ++j) acc += wj[j] * (float)sb[j * 256 + g];
        ac_ws[b * 256 + g] = acc;
        out[(size_t)b * 259 + g] = acc;
    }
    if (tid < 2) out[(size_t)b * 259 + 256 + tid] = hideout[b * 2 + tid];
    if (tid == 0) out[(size_t)b * 259 + 258] = timestep[b];
}

// ---------------------------------------------------------------------------
// 5. CPC: one WG per t. pred/proj -> l2norm -> logits -> log-softmax diag.
// ---------------------------------------------------------------------------
__global__ __launch_bounds__(256, 1) void cpc_kernel(
    const float* __restrict__ ac,      // (128,256) f32
    const float* __restrict__ future,  // (128,12,2) f32
    const float* __restrict__ Wk,      // (12,16,256) f32
    const float* __restrict__ bk,      // (12,16) f32
    const float* __restrict__ Wl,      // (16,2) f32
    const float* __restrict__ bl,      // (16) f32
    float* __restrict__ loss_part)     // (12) f32
{
    __shared__ float pred[128][17];
    __shared__ float proj[128][17];
    __shared__ float red[4];
    const int tid = threadIdx.x, t = blockIdx.x;

    for (int ii = 0; ii < 8; ++ii) {
        int idx = tid + ii * 256;
        int b = idx >> 4, l = idx & 15;
        const float* wrow = Wk + ((size_t)t * 16 + l) * 256;
        const float* arow = ac + b * 256;
        float acc = bk[t * 16 + l];
        for (int g = 0; g < 256; g += 4) {
            float4 w = *(const float4*)(wrow + g);
            float4 a = *(const float4*)(arow + g);
            acc += w.x * a.x + w.y * a.y + w.z * a.z + w.w * a.w;
        }
        pred[b][l] = acc;
        float f0 = future[(b * 12 + t) * 2 + 0];
        float f1 = future[(b * 12 + t) * 2 + 1];
        proj[b][l] = f0 * Wl[l * 2 + 0] + f1 * Wl[l * 2 + 1] + bl[l];
    }
    __syncthreads();
    {
        float* row = (tid < 128) ? pred[tid] : proj[tid - 128];
        float ss = 0.0f;
#pragma unroll
        for (int l = 0; l < 16; ++l) ss += row[l] * row[l];
        float inv = 1.0f / fmaxf(sqrtf(ss), 1e-12f);
#pragma unroll
        for (int l = 0; l < 16; ++l) row[l] *= inv;
    }
    __syncthreads();
    float lsbb = 0.0f;
    if (tid < 128) {
        int b = tid;
        float tf[16];
#pragma unroll
        for (int l = 0; l < 16; ++l) tf[l] = proj[b][l];
        float mx = -1e30f, dbb = 0.0f;
        for (int cc = 0; cc < 128; ++cc) {
            float d = 0.0f;
#pragma unroll
            for (int l = 0; l < 16; ++l) d += tf[l] * pred[cc][l];
            mx = fmaxf(mx, d);
            if (cc == b) dbb = d;
        }
        float den = 0.0f;
        for (int cc = 0; cc < 128; ++cc) {
            float d = 0.0f;
#pragma unroll
            for (int l = 0; l < 16; ++l) d += tf[l] * pred[cc][l];
            den += __expf(d - mx);
        }
        lsbb = dbb - mx - __logf(den);
    }
#pragma unroll
    for (int o = 32; o > 0; o >>= 1) lsbb += __shfl_down(lsbb, o);
    if ((tid & 63) == 0) red[tid >> 6] = lsbb;
    __syncthreads();
    if (tid == 0) loss_part[t] = red[0] + red[1] + red[2] + red[3];
}

__global__ void final_kernel(const float* __restrict__ loss_part,
                             float* __restrict__ out)
{
    if (threadIdx.x == 0) {
        float s = 0.0f;
        for (int t = 0; t < 12; ++t) s += loss_part[t];
        out[33152] = -s / 1536.0f;
    }
}

// ---------------------------------------------------------------------------
extern "C" void kernel_launch(void* const* d_in, const int* in_sizes, int n_in,
                              void* d_out, int out_size, void* d_ws, size_t ws_size,
                              hipStream_t stream)
{
    const float* agent_obs = (const float*)d_in[0];
    const float* future    = (const float*)d_in[1];
    const float* hideout   = (const float*)d_in[2];
    const float* timestep  = (const float*)d_in[3];
    // d_in[4] = num_agents (int, ==16)
    const float* W_ih  = (const float*)d_in[5];
    const float* W_hh  = (const float*)d_in[6];
    const float* b_ih  = (const float*)d_in[7];
    const float* b_hh  = (const float*)d_in[8];
    const float* Wsrc1 = (const float*)d_in[9];
    const float* bsrc1 = (const float*)d_in[10];
    const float* Wdst1 = (const float*)d_in[11];
    const float* bdst1 = (const float*)d_in[12];
    const float* attn1 = (const float*)d_in[13];
    const float* Wsrc2 = (const float*)d_in[14];
    const float* bsrc2 = (const float*)d_in[15];
    const float* Wdst2 = (const float*)d_in[16];
    const float* bdst2 = (const float*)d_in[17];
    const float* attn2 = (const float*)d_in[18];
    const float* Wk    = (const float*)d_in[19];
    const float* bk    = (const float*)d_in[20];
    const float* Wl    = (const float*)d_in[21];
    const float* bl    = (const float*)d_in[22];
    float* out = (float*)d_out;

    char* ws = (char*)d_ws;
    const size_t KB = 1024;
    bf16*  wihb  = (bf16*)(ws);                  // 32 KB  (1024x16)
    bf16*  whhb  = (bf16*)(ws + 32 * KB);        // 512 KB (1024x256)
    bf16*  ws1b  = (bf16*)(ws + 544 * KB);       // 1 MB   (2048x256)
    bf16*  wd1b  = (bf16*)(ws + 1568 * KB);      // 1 MB
    bf16*  ws2b  = (bf16*)(ws + 2592 * KB);      // 128 KB (256x256)
    bf16*  wd2b  = (bf16*)(ws + 2720 * KB);      // 128 KB
    bf16*  hn    = (bf16*)(ws + 2848 * KB);      // 1 MB   (2048x256)
    bf16*  src1  = (bf16*)(ws + 3872 * KB);      // 8 MB   (2048x2048)
    bf16*  dst1  = (bf16*)(ws + 12064 * KB);     // 8 MB
    bf16*  r1    = (bf16*)(ws + 20256 * KB);     // 1 MB   (2048x256)
    bf16*  src2  = (bf16*)(ws + 21280 * KB);     // 1 MB
    bf16*  dst2  = (bf16*)(ws + 22304 * KB);     // 1 MB
    float* acf   = (float*)(ws + 23328 * KB);    // 128 KB (128x256 f32)
    float* lossp = (float*)(ws + 23456 * KB);    // 48 B
    // lstm-only scratch, OVERLAPS src1 region (src1 written after lstm ends):
    int*   flags = (int*)(ws + 3872 * KB);       // 2 KB   (128x4)
    bf16*  hx    = (bf16*)(ws + 3876 * KB);      // 2 MB   (128x2x16x256)

    cvt6<<<1424, 256, 0, stream>>>(W_ih, W_hh, Wsrc1, Wdst1, Wsrc2, Wdst2,
                                   wihb, whhb, ws1b, wd1b, ws2b, wd2b, flags);
    lstm_kernel<<<512, 256, 0, stream>>>(agent_obs, wihb, whhb, b_ih, b_hh,
                                         hn, hx, flags);
    gemm_bias<<<dim3(32, 32), 256, 0, stream>>>(hn, ws1b, bsrc1, src1, 2048, 2048);
    gemm_bias<<<dim3(32, 32), 256, 0, stream>>>(hn, wd1b, bdst1, dst1, 2048, 2048);
    gat1_kernel<<<128, 256, 0, stream>>>(src1, dst1, attn1, r1);
    gemm_bias<<<dim3(4, 32), 256, 0, stream>>>(r1, ws2b, bsrc2, src2, 2048, 256);
    gemm_bias<<<dim3(4, 32), 256, 0, stream>>>(r1, wd2b, bdst2, dst2, 2048, 256);
    gat2_kernel<<<128, 256, 0, stream>>>(src2, dst2, attn2, hideout, timestep, out, acf);
    cpc_kernel<<<12, 256, 0, stream>>>(acf, future, Wk, bk, Wl, bl, lossp);
    final_kernel<<<1, 64, 0, stream>>>(lossp, out);
}

// Round 4
// 2141.990 us; speedup vs baseline: 2.1925x; 2.1925x over previous
//
#include <hip/hip_runtime.h>

// CPCGNN: LSTM(2048 x 128 steps, F=16, H=256) -> GATv2 x2 (16-node graphs) ->
// mean pool -> CPC loss. Inputs/outputs FLOAT32; MFMA paths use bf16 copies.
//
// Round 4: LSTM = one WG per graph (128 WGs), W_hh streamed through LDS with
// global_load_lds (16B), 4-buffer x 32KB ring, depth-2 prefetch, counted
// vmcnt(8) + raw s_barrier per chunk (never drained). No cross-WG sync.

typedef __bf16 bf16;
typedef bf16 bf16x4 __attribute__((ext_vector_type(4)));
typedef bf16 bf16x8 __attribute__((ext_vector_type(8)));
typedef float f32x4 __attribute__((ext_vector_type(4)));

__device__ __forceinline__ float fast_sigmoid(float x) {
    return __builtin_amdgcn_rcpf(1.0f + __expf(-x));
}
__device__ __forceinline__ float fast_tanh(float x) {
    return 2.0f * __builtin_amdgcn_rcpf(1.0f + __expf(-2.0f * x)) - 1.0f;
}
__device__ __forceinline__ bf16x8 zero8() {
    bf16x8 z;
#pragma unroll
    for (int i = 0; i < 8; ++i) z[i] = (bf16)0.0f;
    return z;
}
__device__ __forceinline__ bf16x8 load8_bf(const float* p) {
    float4 a = *(const float4*)p;
    float4 b = *(const float4*)(p + 4);
    bf16x8 r;
    r[0] = (bf16)a.x; r[1] = (bf16)a.y; r[2] = (bf16)a.z; r[3] = (bf16)a.w;
    r[4] = (bf16)b.x; r[5] = (bf16)b.y; r[6] = (bf16)b.z; r[7] = (bf16)b.w;
    return r;
}

// ---------------------------------------------------------------------------
// 0. Weight f32 -> bf16. W_hh is written CHUNK-MAJOR for linear LDS staging:
//    chunk ic = kc*2+gh covers rows [gh*512, gh*512+512) x k [kc*32, kc*32+32),
//    layout whh2[ic][512][32].
// ---------------------------------------------------------------------------
__global__ __launch_bounds__(256, 1) void cvt6(
    const float* __restrict__ s0, const float* __restrict__ s1,
    const float* __restrict__ s2, const float* __restrict__ s3,
    const float* __restrict__ s4, const float* __restrict__ s5,
    bf16* __restrict__ d0, bf16* __restrict__ d1, bf16* __restrict__ d2,
    bf16* __restrict__ d3, bf16* __restrict__ d4, bf16* __restrict__ d5)
{
    const int n0 = 16384, n1 = 262144, n2 = 524288, n3 = 524288, n4 = 65536;
    int loc = (blockIdx.x * 256 + threadIdx.x) * 4;
    const float* s; bf16* d; int dst;
    if (loc < n0)              { s = s0; d = d0; dst = loc; }
    else if ((loc -= n0) < n1) {
        s = s1; d = d1;
        int n = loc >> 8, k = loc & 255;
        dst = ((((k >> 5) << 1) | (n >> 9)) << 14) + ((n & 511) << 5) + (k & 31);
    }
    else if ((loc -= n1) < n2) { s = s2; d = d2; dst = loc; }
    else if ((loc -= n2) < n3) { s = s3; d = d3; dst = loc; }
    else if ((loc -= n3) < n4) { s = s4; d = d4; dst = loc; }
    else                       { loc -= n4; s = s5; d = d5; dst = loc; }
    float4 v = *(const float4*)(s + loc);
    bf16x4 o;
    o[0] = (bf16)v.x; o[1] = (bf16)v.y; o[2] = (bf16)v.z; o[3] = (bf16)v.w;
    *(bf16x4*)(d + dst) = o;
}

// ---------------------------------------------------------------------------
// 1. LSTM. WG b owns graph b (16 rows). Wave w owns taus {w,w+4,w+8,w+12},
//    all 4 gates. Per step: 16 chunk-iters; chunk (kc,gh) = 512 rows x 32 k
//    staged via global_load_lds into a 4x32KB LDS ring (depth-2 prefetch).
//    Per chunk-iter per wave: 8 gload_lds (next+1 chunk) + 1 A ds_read +
//    8 B ds_read_b128 + 8 MFMA, then counted vmcnt(8)+barrier.
// ---------------------------------------------------------------------------
__global__ __launch_bounds__(256, 1) void lstm_kernel(
    const float* __restrict__ agent_obs,  // (128,128,16,16) f32
    const bf16* __restrict__ W_ih,        // (1024,16) bf16
    const bf16* __restrict__ whh2,        // (16,512,32) bf16 chunk-major
    const float* __restrict__ b_ih,
    const float* __restrict__ b_hh,
    bf16* __restrict__ hn)                // (2048,256) bf16
{
    __shared__ bf16 wbuf[4][16384];       // 128 KB ring
    __shared__ bf16 hbuf[2][16][264];     // 16.5 KB double-buffered h
    const int tid  = threadIdx.x;
    const int lane = tid & 63;
    const int wv   = tid >> 6;
    const int col  = lane & 15;           // A-row (agent) / B-col (within tau)
    const int grp  = lane >> 4;           // k-group
    const int b    = blockIdx.x;

    for (int i = tid; i < 2 * 16 * 264; i += 256) (&hbuf[0][0][0])[i] = (bf16)0.0f;

    // per-lane invariants
    float bias[4][4];
    bf16x8 wih[4][4];
#pragma unroll
    for (int G = 0; G < 4; ++G)
#pragma unroll
        for (int q = 0; q < 4; ++q) {
            int tau = wv + 4 * q;
            int n = G * 256 + tau * 16 + col;
            bias[G][q] = b_ih[n] + b_hh[n];
            wih[G][q] = (grp < 2) ? *(const bf16x8*)&W_ih[n * 16 + grp * 8] : zero8();
        }
    f32x4 cst[4];
#pragma unroll
    for (int q = 0; q < 4; ++q) cst[q] = (f32x4){0.0f, 0.0f, 0.0f, 0.0f};

    // stage one 32KB chunk: 8 x (256 thr x 16B)
    auto stage = [&](int chunkid, int bufid) {
        const bf16* gs = whh2 + (size_t)chunkid * 16384 + wv * 512 + lane * 8;
        bf16* ls = &wbuf[bufid][wv * 512];
#pragma unroll
        for (int t2 = 0; t2 < 8; ++t2)
            __builtin_amdgcn_global_load_lds((const void*)(gs + t2 * 2048),
                                             (void*)(ls + t2 * 2048), 16, 0, 0);
    };

    const float* xb = agent_obs + (size_t)b * 32768;
    bf16x8 ax = (grp < 2) ? load8_bf(xb + col * 16 + grp * 8) : zero8();

    stage(0, 0);
    stage(1, 1);
    asm volatile("s_waitcnt vmcnt(8) lgkmcnt(0)\n\ts_barrier" ::: "memory");

    for (int s = 0; s < 128; ++s) {
        const int pr = s & 1, pw = pr ^ 1;
        f32x4 acc[4][4];
#pragma unroll
        for (int G = 0; G < 4; ++G)
#pragma unroll
            for (int q = 0; q < 4; ++q) {
                float bs_ = bias[G][q];
                acc[G][q] = (f32x4){bs_, bs_, bs_, bs_};
                acc[G][q] = __builtin_amdgcn_mfma_f32_16x16x32_bf16(
                    ax, wih[G][q], acc[G][q], 0, 0, 0);
            }
#pragma unroll
        for (int ic = 0; ic < 16; ++ic) {
            stage((ic + 2) & 15, (ic + 2) & 3);
            const int kc = ic >> 1, gh = ic & 1;
            bf16x8 ah = *(const bf16x8*)&hbuf[pr][col][kc * 32 + grp * 8];
#pragma unroll
            for (int gq = 0; gq < 8; ++gq) {
                const int G = gh * 2 + (gq >> 2), q = gq & 3;
                const int tau = wv + 4 * q;
                bf16x8 bw = *(const bf16x8*)
                    &wbuf[ic & 3][((gq >> 2) * 256 + tau * 16 + col) * 32 + grp * 8];
                acc[G][q] = __builtin_amdgcn_mfma_f32_16x16x32_bf16(
                    ah, bw, acc[G][q], 0, 0, 0);
            }
            if (ic == 15) {
                // prefetch next step's x (its implicit wait also covers c0/c1)
                const int sn = (s < 127) ? s + 1 : 127;
                bf16x8 axn = (grp < 2)
                                 ? load8_bf(xb + sn * 256 + col * 16 + grp * 8)
                                 : zero8();
                // gates
#pragma unroll
                for (int q = 0; q < 4; ++q) {
                    const int tau = wv + 4 * q;
#pragma unroll
                    for (int r = 0; r < 4; ++r) {
                        float iv = fast_sigmoid(acc[0][q][r]);
                        float fv = fast_sigmoid(acc[1][q][r]);
                        float gv = fast_tanh(acc[2][q][r]);
                        float ov = fast_sigmoid(acc[3][q][r]);
                        float cn = fv * cst[q][r] + iv * gv;
                        cst[q][r] = cn;
                        float hv = ov * fast_tanh(cn);
                        if (s == 127)
                            hn[((size_t)b * 16 + grp * 4 + r) * 256 + tau * 16 + col]
                                = (bf16)hv;
                        else
                            hbuf[pw][grp * 4 + r][tau * 16 + col] = (bf16)hv;
                    }
                }
                ax = axn;
            }
            asm volatile("s_waitcnt vmcnt(8) lgkmcnt(0)\n\ts_barrier" ::: "memory");
        }
    }
}

// ---------------------------------------------------------------------------
// 2. GEMM: C[M,N] = A[M,256] @ W[N,256]^T + bias. A,W,C bf16; bias f32.
// ---------------------------------------------------------------------------
__global__ __launch_bounds__(256, 1) void gemm_bias(
    const bf16* __restrict__ A, const bf16* __restrict__ W,
    const float* __restrict__ bias, bf16* __restrict__ C, int M, int N)
{
    const int tid = threadIdx.x, lane = tid & 63, wv = tid >> 6;
    const int col = lane & 15, grp = lane >> 4;
    const int n = blockIdx.x * 64 + wv * 16 + col;
    const int bm = blockIdx.y * 64;
    float bs = bias[n];
    f32x4 acc[4];
#pragma unroll
    for (int mt = 0; mt < 4; ++mt) acc[mt] = (f32x4){bs, bs, bs, bs};
#pragma unroll
    for (int kc = 0; kc < 8; ++kc) {
        bf16x8 bw = *(const bf16x8*)&W[(size_t)n * 256 + kc * 32 + grp * 8];
#pragma unroll
        for (int mt = 0; mt < 4; ++mt) {
            bf16x8 aa = *(const bf16x8*)
                &A[(size_t)(bm + mt * 16 + col) * 256 + kc * 32 + grp * 8];
            acc[mt] = __builtin_amdgcn_mfma_f32_16x16x32_bf16(aa, bw, acc[mt], 0, 0, 0);
        }
    }
#pragma unroll
    for (int mt = 0; mt < 4; ++mt)
#pragma unroll
        for (int r = 0; r < 4; ++r)
            C[(size_t)(bm + mt * 16 + grp * 4 + r) * N + n] = (bf16)acc[mt][r];
}

// ---------------------------------------------------------------------------
// 3. GATv2 layer 1: scores + edge softmax (no self) + head-mean aggregation.
// ---------------------------------------------------------------------------
__global__ __launch_bounds__(256, 1) void gat1_kernel(
    const bf16* __restrict__ src,    // (2048, 2048) = (b*16+n, h*256+f)
    const bf16* __restrict__ dst,
    const float* __restrict__ attn,  // (8,256) f32
    bf16* __restrict__ r1)           // (2048, 256)
{
    __shared__ float sal[2048];      // (i*16+j)*8+h
    const int tid = threadIdx.x, b = blockIdx.x;
    const bf16* sb = src + (size_t)b * 32768;
    const bf16* db = dst + (size_t)b * 32768;

    for (int ii = 0; ii < 8; ++ii) {
        int trip = tid + ii * 256;            // i*128 + j*8 + h
        int i = trip >> 7, j = (trip >> 3) & 15, h = trip & 7;
        const bf16* ps = sb + j * 2048 + h * 256;
        const bf16* pd = db + i * 2048 + h * 256;
        const float* pa = attn + h * 256;
        float acc = 0.0f;
        for (int f8 = 0; f8 < 32; ++f8) {
            bf16x8 vs = *(const bf16x8*)(ps + f8 * 8);
            bf16x8 vd = *(const bf16x8*)(pd + f8 * 8);
            float4 a0 = *(const float4*)(pa + f8 * 8);
            float4 a1 = *(const float4*)(pa + f8 * 8 + 4);
            float av[8] = {a0.x, a0.y, a0.z, a0.w, a1.x, a1.y, a1.z, a1.w};
#pragma unroll
            for (int e = 0; e < 8; ++e) {
                float v = (float)vs[e] + (float)vd[e];
                v = v > 0.0f ? v : 0.2f * v;
                acc += v * av[e];
            }
        }
        sal[trip] = acc;
    }
    __syncthreads();
    if (tid < 128) {                          // softmax over j != i
        int i = tid >> 3, h = tid & 7;
        float m = -1e30f;
#pragma unroll
        for (int j = 0; j < 16; ++j)
            if (j != i) m = fmaxf(m, sal[(i * 16 + j) * 8 + h]);
        float ex[16], den = 0.0f;
#pragma unroll
        for (int j = 0; j < 16; ++j) {
            ex[j] = (j == i) ? 0.0f : __expf(sal[(i * 16 + j) * 8 + h] - m);
            den += ex[j];
        }
        float rd = 1.0f / den;
#pragma unroll
        for (int j = 0; j < 16; ++j) sal[(i * 16 + j) * 8 + h] = ex[j] * rd;
    }
    __syncthreads();
    {
        int i = tid >> 4, fb = tid & 15;
        for (int it = 0; it < 16; ++it) {
            int f = fb + it * 16;
            float acc = 0.0f;
            for (int j = 0; j < 16; ++j) {
                const bf16* ps = sb + j * 2048 + f;
#pragma unroll
                for (int h = 0; h < 8; ++h)
                    acc += sal[(i * 16 + j) * 8 + h] * (float)ps[h * 256];
            }
            r1[((size_t)b * 16 + i) * 256 + f] = (bf16)(acc * 0.125f);
        }
    }
}

// ---------------------------------------------------------------------------
// 4. GATv2 layer 2 (1 head) fused with node-mean + d_out row writes.
// ---------------------------------------------------------------------------
__global__ __launch_bounds__(256, 1) void gat2_kernel(
    const bf16* __restrict__ src2,   // (2048,256)
    const bf16* __restrict__ dst2,
    const float* __restrict__ attn2, // (256) f32
    const float* __restrict__ hideout,   // (128,2) f32
    const float* __restrict__ timestep,  // (128,1) f32
    float* __restrict__ out,             // (128,259)+loss f32
    float* __restrict__ ac_ws)           // (128,256) f32
{
    __shared__ float sal[256];
    __shared__ float wj[16];
    const int tid = threadIdx.x, b = blockIdx.x;
    const bf16* sb = src2 + (size_t)b * 4096;
    const bf16* db = dst2 + (size_t)b * 4096;
    {
        int i = tid >> 4, j = tid & 15;
        const bf16* ps = sb + j * 256;
        const bf16* pd = db + i * 256;
        float acc = 0.0f;
        for (int g8 = 0; g8 < 32; ++g8) {
            bf16x8 vs = *(const bf16x8*)(ps + g8 * 8);
            bf16x8 vd = *(const bf16x8*)(pd + g8 * 8);
            float4 a0 = *(const float4*)(attn2 + g8 * 8);
            float4 a1 = *(const float4*)(attn2 + g8 * 8 + 4);
            float av[8] = {a0.x, a0.y, a0.z, a0.w, a1.x, a1.y, a1.z, a1.w};
#pragma unroll
            for (int e = 0; e < 8; ++e) {
                float v = (float)vs[e] + (float)vd[e];
                v = v > 0.0f ? v : 0.2f * v;
                acc += v * av[e];
            }
        }
        sal[tid] = acc;
    }
    __syncthreads();
    if (tid < 16) {
        int i = tid;
        float m = -1e30f;
#pragma unroll
        for (int j = 0; j < 16; ++j)
            if (j != i) m = fmaxf(m, sal[i * 16 + j]);
        float ex[16], den = 0.0f;
#pragma unroll
        for (int j = 0; j < 16; ++j) {
            ex[j] = (j == i) ? 0.0f : __expf(sal[i * 16 + j] - m);
            den += ex[j];
        }
        float rd = 1.0f / den;
#pragma unroll
        for (int j = 0; j < 16; ++j) sal[i * 16 + j] = ex[j] * rd;
    }
    __syncthreads();
    if (tid < 16) {
        float a = 0.0f;
#pragma unroll
        for (int i = 0; i < 16; ++i) a += sal[i * 16 + tid];
        wj[tid] = a * (1.0f / 16.0f);
    }
    __syncthreads();
    {
        int g = tid;
        float acc = 0.0f;
#pragma unroll
        for (int j = 0; j < 16; ++j) acc += wj[j] * (float)sb[j * 256 + g];
        ac_ws[b * 256 + g] = acc;
        out[(size_t)b * 259 + g] = acc;
    }
    if (tid < 2) out[(size_t)b * 259 + 256 + tid] = hideout[b * 2 + tid];
    if (tid == 0) out[(size_t)b * 259 + 258] = timestep[b];
}

// ---------------------------------------------------------------------------
// 5. CPC: one WG per t. pred/proj -> l2norm -> logits -> log-softmax diag.
// ---------------------------------------------------------------------------
__global__ __launch_bounds__(256, 1) void cpc_kernel(
    const float* __restrict__ ac,      // (128,256) f32
    const float* __restrict__ future,  // (128,12,2) f32
    const float* __restrict__ Wk,      // (12,16,256) f32
    const float* __restrict__ bk,      // (12,16) f32
    const float* __restrict__ Wl,      // (16,2) f32
    const float* __restrict__ bl,      // (16) f32
    float* __restrict__ loss_part)     // (12) f32
{
    __shared__ float pred[128][17];
    __shared__ float proj[128][17];
    __shared__ float red[4];
    const int tid = threadIdx.x, t = blockIdx.x;

    for (int ii = 0; ii < 8; ++ii) {
        int idx = tid + ii * 256;
        int b = idx >> 4, l = idx & 15;
        const float* wrow = Wk + ((size_t)t * 16 + l) * 256;
        const float* arow = ac + b * 256;
        float acc = bk[t * 16 + l];
        for (int g = 0; g < 256; g += 4) {
            float4 w = *(const float4*)(wrow + g);
            float4 a = *(const float4*)(arow + g);
            acc += w.x * a.x + w.y * a.y + w.z * a.z + w.w * a.w;
        }
        pred[b][l] = acc;
        float f0 = future[(b * 12 + t) * 2 + 0];
        float f1 = future[(b * 12 + t) * 2 + 1];
        proj[b][l] = f0 * Wl[l * 2 + 0] + f1 * Wl[l * 2 + 1] + bl[l];
    }
    __syncthreads();
    {
        float* row = (tid < 128) ? pred[tid] : proj[tid - 128];
        float ss = 0.0f;
#pragma unroll
        for (int l = 0; l < 16; ++l) ss += row[l] * row[l];
        float inv = 1.0f / fmaxf(sqrtf(ss), 1e-12f);
#pragma unroll
        for (int l = 0; l < 16; ++l) row[l] *= inv;
    }
    __syncthreads();
    float lsbb = 0.0f;
    if (tid < 128) {
        int b = tid;
        float tf[16];
#pragma unroll
        for (int l = 0; l < 16; ++l) tf[l] = proj[b][l];
        float mx = -1e30f, dbb = 0.0f;
        for (int cc = 0; cc < 128; ++cc) {
            float d = 0.0f;
#pragma unroll
            for (int l = 0; l < 16; ++l) d += tf[l] * pred[cc][l];
            mx = fmaxf(mx, d);
            if (cc == b) dbb = d;
        }
        float den = 0.0f;
        for (int cc = 0; cc < 128; ++cc) {
            float d = 0.0f;
#pragma unroll
            for (int l = 0; l < 16; ++l) d += tf[l] * pred[cc][l];
            den += __expf(d - mx);
        }
        lsbb = dbb - mx - __logf(den);
    }
#pragma unroll
    for (int o = 32; o > 0; o >>= 1) lsbb += __shfl_down(lsbb, o);
    if ((tid & 63) == 0) red[tid >> 6] = lsbb;
    __syncthreads();
    if (tid == 0) loss_part[t] = red[0] + red[1] + red[2] + red[3];
}

__global__ void final_kernel(const float* __restrict__ loss_part,
                             float* __restrict__ out)
{
    if (threadIdx.x == 0) {
        float s = 0.0f;
        for (int t = 0; t < 12; ++t) s += loss_part[t];
        out[33152] = -s / 1536.0f;
    }
}

// ---------------------------------------------------------------------------
extern "C" void kernel_launch(void* const* d_in, const int* in_sizes, int n_in,
                              void* d_out, int out_size, void* d_ws, size_t ws_size,
                              hipStream_t stream)
{
    const float* agent_obs = (const float*)d_in[0];
    const float* future    = (const float*)d_in[1];
    const float* hideout   = (const float*)d_in[2];
    const float* timestep  = (const float*)d_in[3];
    // d_in[4] = num_agents (int, ==16)
    const float* W_ih  = (const float*)d_in[5];
    const float* W_hh  = (const float*)d_in[6];
    const float* b_ih  = (const float*)d_in[7];
    const float* b_hh  = (const float*)d_in[8];
    const float* Wsrc1 = (const float*)d_in[9];
    const float* bsrc1 = (const float*)d_in[10];
    const float* Wdst1 = (const float*)d_in[11];
    const float* bdst1 = (const float*)d_in[12];
    const float* attn1 = (const float*)d_in[13];
    const float* Wsrc2 = (const float*)d_in[14];
    const float* bsrc2 = (const float*)d_in[15];
    const float* Wdst2 = (const float*)d_in[16];
    const float* bdst2 = (const float*)d_in[17];
    const float* attn2 = (const float*)d_in[18];
    const float* Wk    = (const float*)d_in[19];
    const float* bk    = (const float*)d_in[20];
    const float* Wl    = (const float*)d_in[21];
    const float* bl    = (const float*)d_in[22];
    float* out = (float*)d_out;

    char* ws = (char*)d_ws;
    const size_t KB = 1024;
    bf16*  wihb  = (bf16*)(ws);                  // 32 KB  (1024x16)
    bf16*  whh2  = (bf16*)(ws + 32 * KB);        // 512 KB (16,512,32) chunked
    bf16*  ws1b  = (bf16*)(ws + 544 * KB);       // 1 MB   (2048x256)
    bf16*  wd1b  = (bf16*)(ws + 1568 * KB);      // 1 MB
    bf16*  ws2b  = (bf16*)(ws + 2592 * KB);      // 128 KB (256x256)
    bf16*  wd2b  = (bf16*)(ws + 2720 * KB);      // 128 KB
    bf16*  hn    = (bf16*)(ws + 2848 * KB);      // 1 MB   (2048x256)
    bf16*  src1  = (bf16*)(ws + 3872 * KB);      // 8 MB   (2048x2048)
    bf16*  dst1  = (bf16*)(ws + 12064 * KB);     // 8 MB
    bf16*  r1    = (bf16*)(ws + 20256 * KB);     // 1 MB   (2048x256)
    bf16*  src2  = (bf16*)(ws + 21280 * KB);     // 1 MB
    bf16*  dst2  = (bf16*)(ws + 22304 * KB);     // 1 MB
    float* acf   = (float*)(ws + 23328 * KB);    // 128 KB (128x256 f32)
    float* lossp = (float*)(ws + 23456 * KB);    // 48 B

    cvt6<<<1424, 256, 0, stream>>>(W_ih, W_hh, Wsrc1, Wdst1, Wsrc2, Wdst2,
                                   wihb, whh2, ws1b, wd1b, ws2b, wd2b);
    lstm_kernel<<<128, 256, 0, stream>>>(agent_obs, wihb, whh2, b_ih, b_hh, hn);
    gemm_bias<<<dim3(32, 32), 256, 0, stream>>>(hn, ws1b, bsrc1, src1, 2048, 2048);
    gemm_bias<<<dim3(32, 32), 256, 0, stream>>>(hn, wd1b, bdst1, dst1, 2048, 2048);
    gat1_kernel<<<128, 256, 0, stream>>>(src1, dst1, attn1, r1);
    gemm_bias<<<dim3(4, 32), 256, 0, stream>>>(r1, ws2b, bsrc2, src2, 2048, 256);
    gemm_bias<<<dim3(4, 32), 256, 0, stream>>>(r1, wd2b, bdst2, dst2, 2048, 256);
    gat2_kernel<<<128, 256, 0, stream>>>(src2, dst2, attn2, hideout, timestep, out, acf);
    cpc_kernel<<<12, 256, 0, stream>>>(acf, future, Wk, bk, Wl, bl, lossp);
    final_kernel<<<1, 64, 0, stream>>>(lossp, out);
}

// Round 5
// 1726.492 us; speedup vs baseline: 2.7202x; 1.2407x over previous
//
#include <hip/hip_runtime.h>

// CPCGNN: LSTM(2048 x 128 steps, F=16, H=256) -> GATv2 x2 (16-node graphs) ->
// mean pool -> CPC loss. Inputs/outputs FLOAT32; MFMA paths use bf16 copies.
//
// Round 5: LSTM = 128 WGs x 1024 threads (16 waves = 4/SIMD). Wave w owns
// tau=w (16 h-cols) for all 4 gates. W_hh read directly global->VGPR from the
// chunk-major whh2 layout (each wave instr = contiguous 1KB), depth-2 pipeline
// over kc, h double-buffered in LDS, ONE barrier per step. No global_load_lds,
// no cross-WG sync. TLP (16 waves/CU) hides L2 latency.

typedef __bf16 bf16;
typedef bf16 bf16x4 __attribute__((ext_vector_type(4)));
typedef bf16 bf16x8 __attribute__((ext_vector_type(8)));
typedef float f32x4 __attribute__((ext_vector_type(4)));

__device__ __forceinline__ float fast_sigmoid(float x) {
    return __builtin_amdgcn_rcpf(1.0f + __expf(-x));
}
__device__ __forceinline__ float fast_tanh(float x) {
    return 2.0f * __builtin_amdgcn_rcpf(1.0f + __expf(-2.0f * x)) - 1.0f;
}
__device__ __forceinline__ bf16x8 zero8() {
    bf16x8 z;
#pragma unroll
    for (int i = 0; i < 8; ++i) z[i] = (bf16)0.0f;
    return z;
}
__device__ __forceinline__ bf16x8 load8_bf(const float* p) {
    float4 a = *(const float4*)p;
    float4 b = *(const float4*)(p + 4);
    bf16x8 r;
    r[0] = (bf16)a.x; r[1] = (bf16)a.y; r[2] = (bf16)a.z; r[3] = (bf16)a.w;
    r[4] = (bf16)b.x; r[5] = (bf16)b.y; r[6] = (bf16)b.z; r[7] = (bf16)b.w;
    return r;
}

// ---------------------------------------------------------------------------
// 0. Weight f32 -> bf16. W_hh chunk-major: chunk ic = kc*2 + (n>>9) holds
//    rows (n&511) x k (kc*32..kc*32+32), layout whh2[16][512][32].
// ---------------------------------------------------------------------------
__global__ __launch_bounds__(256, 1) void cvt6(
    const float* __restrict__ s0, const float* __restrict__ s1,
    const float* __restrict__ s2, const float* __restrict__ s3,
    const float* __restrict__ s4, const float* __restrict__ s5,
    bf16* __restrict__ d0, bf16* __restrict__ d1, bf16* __restrict__ d2,
    bf16* __restrict__ d3, bf16* __restrict__ d4, bf16* __restrict__ d5)
{
    const int n0 = 16384, n1 = 262144, n2 = 524288, n3 = 524288, n4 = 65536;
    int loc = (blockIdx.x * 256 + threadIdx.x) * 4;
    const float* s; bf16* d; int dst;
    if (loc < n0)              { s = s0; d = d0; dst = loc; }
    else if ((loc -= n0) < n1) {
        s = s1; d = d1;
        int n = loc >> 8, k = loc & 255;
        dst = ((((k >> 5) << 1) | (n >> 9)) << 14) + ((n & 511) << 5) + (k & 31);
    }
    else if ((loc -= n1) < n2) { s = s2; d = d2; dst = loc; }
    else if ((loc -= n2) < n3) { s = s3; d = d3; dst = loc; }
    else if ((loc -= n3) < n4) { s = s4; d = d4; dst = loc; }
    else                       { loc -= n4; s = s5; d = d5; dst = loc; }
    float4 v = *(const float4*)(s + loc);
    bf16x4 o;
    o[0] = (bf16)v.x; o[1] = (bf16)v.y; o[2] = (bf16)v.z; o[3] = (bf16)v.w;
    *(bf16x4*)(d + dst) = o;
}

// ---------------------------------------------------------------------------
// 1. LSTM. WG b = graph b (16 rows). 16 waves; wave w owns tau=w: gate-cols
//    n = G*256 + w*16 + col for G=0..3. Per step per wave: 32 direct 16B
//    W loads (depth-2 pipelined over kc), 36 MFMA, gates, 1 barrier.
// ---------------------------------------------------------------------------
__global__ __launch_bounds__(1024, 4) void lstm_kernel(
    const float* __restrict__ agent_obs,  // (128,128,16,16) f32
    const bf16* __restrict__ W_ih,        // (1024,16) bf16
    const bf16* __restrict__ whh2,        // (16,512,32) bf16 chunk-major
    const float* __restrict__ b_ih,
    const float* __restrict__ b_hh,
    bf16* __restrict__ hn)                // (2048,256) bf16
{
    __shared__ bf16 hbuf[2][16][264];     // +8 pad; double-buffered h
    const int tid  = threadIdx.x;
    const int lane = tid & 63;
    const int w    = tid >> 6;            // wave id = tau
    const int col  = lane & 15;           // A-row (agent) / B-col (within tau)
    const int grp  = lane >> 4;           // k-group
    const int b    = blockIdx.x;

    for (int i = tid; i < 2 * 16 * 264; i += 1024) (&hbuf[0][0][0])[i] = (bf16)0.0f;

    // per-lane invariants
    float bias[4];
    bf16x8 wih[4];
    const bf16* wp[4];                    // &whh2[chunk(G,kc=0)][r512][grp*8]
#pragma unroll
    for (int G = 0; G < 4; ++G) {
        int n = G * 256 + w * 16 + col;
        bias[G] = b_ih[n] + b_hh[n];
        wih[G] = (grp < 2) ? *(const bf16x8*)&W_ih[n * 16 + grp * 8] : zero8();
        int gh = G >> 1;
        int r512 = (n & 511);
        wp[G] = whh2 + gh * 16384 + r512 * 32 + grp * 8;  // +kc*32768 per kc
    }
    f32x4 c = (f32x4){0.0f, 0.0f, 0.0f, 0.0f};

    const float* xb = agent_obs + (size_t)b * 32768;
    bf16x8 ax = (grp < 2) ? load8_bf(xb + col * 16 + grp * 8) : zero8();

    __syncthreads();

    for (int s = 0; s < 128; ++s) {
        const int pr = s & 1, pw = pr ^ 1;
        f32x4 acc[4];
#pragma unroll
        for (int G = 0; G < 4; ++G) {
            float bs_ = bias[G];
            acc[G] = (f32x4){bs_, bs_, bs_, bs_};
            acc[G] = __builtin_amdgcn_mfma_f32_16x16x32_bf16(ax, wih[G], acc[G], 0, 0, 0);
        }
        // prefetch next step's x early (independent of this step)
        bf16x8 axn = (s < 127 && grp < 2)
                         ? load8_bf(xb + (s + 1) * 256 + col * 16 + grp * 8)
                         : zero8();
        // depth-2 pipelined K loop: 4 loads in flight while 4 MFMAs run
        bf16x8 bw[4], bwn[4];
#pragma unroll
        for (int G = 0; G < 4; ++G) bw[G] = *(const bf16x8*)(wp[G]);
#pragma unroll
        for (int kc = 0; kc < 8; ++kc) {
            if (kc < 7) {
#pragma unroll
                for (int G = 0; G < 4; ++G)
                    bwn[G] = *(const bf16x8*)(wp[G] + (kc + 1) * 32768);
            }
            bf16x8 ah = *(const bf16x8*)&hbuf[pr][col][kc * 32 + grp * 8];
#pragma unroll
            for (int G = 0; G < 4; ++G)
                acc[G] = __builtin_amdgcn_mfma_f32_16x16x32_bf16(ah, bw[G], acc[G], 0, 0, 0);
#pragma unroll
            for (int G = 0; G < 4; ++G) bw[G] = bwn[G];
        }
        // gates: lane holds rows m=grp*4+r, col j=w*16+col
#pragma unroll
        for (int r = 0; r < 4; ++r) {
            float iv = fast_sigmoid(acc[0][r]);
            float fv = fast_sigmoid(acc[1][r]);
            float gv = fast_tanh(acc[2][r]);
            float ov = fast_sigmoid(acc[3][r]);
            float cn = fv * c[r] + iv * gv;
            c[r] = cn;
            float hv = ov * fast_tanh(cn);
            int m = grp * 4 + r, j = w * 16 + col;
            if (s == 127) hn[((size_t)b * 16 + m) * 256 + j] = (bf16)hv;
            else          hbuf[pw][m][j] = (bf16)hv;
        }
        ax = axn;
        __syncthreads();
    }
}

// ---------------------------------------------------------------------------
// 2. GEMM: C[M,N] = A[M,256] @ W[N,256]^T + bias. A,W,C bf16; bias f32.
// ---------------------------------------------------------------------------
__global__ __launch_bounds__(256, 1) void gemm_bias(
    const bf16* __restrict__ A, const bf16* __restrict__ W,
    const float* __restrict__ bias, bf16* __restrict__ C, int M, int N)
{
    const int tid = threadIdx.x, lane = tid & 63, wv = tid >> 6;
    const int col = lane & 15, grp = lane >> 4;
    const int n = blockIdx.x * 64 + wv * 16 + col;
    const int bm = blockIdx.y * 64;
    float bs = bias[n];
    f32x4 acc[4];
#pragma unroll
    for (int mt = 0; mt < 4; ++mt) acc[mt] = (f32x4){bs, bs, bs, bs};
#pragma unroll
    for (int kc = 0; kc < 8; ++kc) {
        bf16x8 bw = *(const bf16x8*)&W[(size_t)n * 256 + kc * 32 + grp * 8];
#pragma unroll
        for (int mt = 0; mt < 4; ++mt) {
            bf16x8 aa = *(const bf16x8*)
                &A[(size_t)(bm + mt * 16 + col) * 256 + kc * 32 + grp * 8];
            acc[mt] = __builtin_amdgcn_mfma_f32_16x16x32_bf16(aa, bw, acc[mt], 0, 0, 0);
        }
    }
#pragma unroll
    for (int mt = 0; mt < 4; ++mt)
#pragma unroll
        for (int r = 0; r < 4; ++r)
            C[(size_t)(bm + mt * 16 + grp * 4 + r) * N + n] = (bf16)acc[mt][r];
}

// ---------------------------------------------------------------------------
// 3. GATv2 layer 1: scores + edge softmax (no self) + head-mean aggregation.
// ---------------------------------------------------------------------------
__global__ __launch_bounds__(256, 1) void gat1_kernel(
    const bf16* __restrict__ src,    // (2048, 2048) = (b*16+n, h*256+f)
    const bf16* __restrict__ dst,
    const float* __restrict__ attn,  // (8,256) f32
    bf16* __restrict__ r1)           // (2048, 256)
{
    __shared__ float sal[2048];      // (i*16+j)*8+h
    const int tid = threadIdx.x, b = blockIdx.x;
    const bf16* sb = src + (size_t)b * 32768;
    const bf16* db = dst + (size_t)b * 32768;

    for (int ii = 0; ii < 8; ++ii) {
        int trip = tid + ii * 256;            // i*128 + j*8 + h
        int i = trip >> 7, j = (trip >> 3) & 15, h = trip & 7;
        const bf16* ps = sb + j * 2048 + h * 256;
        const bf16* pd = db + i * 2048 + h * 256;
        const float* pa = attn + h * 256;
        float acc = 0.0f;
        for (int f8 = 0; f8 < 32; ++f8) {
            bf16x8 vs = *(const bf16x8*)(ps + f8 * 8);
            bf16x8 vd = *(const bf16x8*)(pd + f8 * 8);
            float4 a0 = *(const float4*)(pa + f8 * 8);
            float4 a1 = *(const float4*)(pa + f8 * 8 + 4);
            float av[8] = {a0.x, a0.y, a0.z, a0.w, a1.x, a1.y, a1.z, a1.w};
#pragma unroll
            for (int e = 0; e < 8; ++e) {
                float v = (float)vs[e] + (float)vd[e];
                v = v > 0.0f ? v : 0.2f * v;
                acc += v * av[e];
            }
        }
        sal[trip] = acc;
    }
    __syncthreads();
    if (tid < 128) {                          // softmax over j != i
        int i = tid >> 3, h = tid & 7;
        float m = -1e30f;
#pragma unroll
        for (int j = 0; j < 16; ++j)
            if (j != i) m = fmaxf(m, sal[(i * 16 + j) * 8 + h]);
        float ex[16], den = 0.0f;
#pragma unroll
        for (int j = 0; j < 16; ++j) {
            ex[j] = (j == i) ? 0.0f : __expf(sal[(i * 16 + j) * 8 + h] - m);
            den += ex[j];
        }
        float rd = 1.0f / den;
#pragma unroll
        for (int j = 0; j < 16; ++j) sal[(i * 16 + j) * 8 + h] = ex[j] * rd;
    }
    __syncthreads();
    {
        int i = tid >> 4, fb = tid & 15;
        for (int it = 0; it < 16; ++it) {
            int f = fb + it * 16;
            float acc = 0.0f;
            for (int j = 0; j < 16; ++j) {
                const bf16* ps = sb + j * 2048 + f;
#pragma unroll
                for (int h = 0; h < 8; ++h)
                    acc += sal[(i * 16 + j) * 8 + h] * (float)ps[h * 256];
            }
            r1[((size_t)b * 16 + i) * 256 + f] = (bf16)(acc * 0.125f);
        }
    }
}

// ---------------------------------------------------------------------------
// 4. GATv2 layer 2 (1 head) fused with node-mean + d_out row writes.
// ---------------------------------------------------------------------------
__global__ __launch_bounds__(256, 1) void gat2_kernel(
    const bf16* __restrict__ src2,   // (2048,256)
    const bf16* __restrict__ dst2,
    const float* __restrict__ attn2, // (256) f32
    const float* __restrict__ hideout,   // (128,2) f32
    const float* __restrict__ timestep,  // (128,1) f32
    float* __restrict__ out,             // (128,259)+loss f32
    float* __restrict__ ac_ws)           // (128,256) f32
{
    __shared__ float sal[256];
    __shared__ float wj[16];
    const int tid = threadIdx.x, b = blockIdx.x;
    const bf16* sb = src2 + (size_t)b * 4096;
    const bf16* db = dst2 + (size_t)b * 4096;
    {
        int i = tid >> 4, j = tid & 15;
        const bf16* ps = sb + j * 256;
        const bf16* pd = db + i * 256;
        float acc = 0.0f;
        for (int g8 = 0; g8 < 32; ++g8) {
            bf16x8 vs = *(const bf16x8*)(ps + g8 * 8);
            bf16x8 vd = *(const bf16x8*)(pd + g8 * 8);
            float4 a0 = *(const float4*)(attn2 + g8 * 8);
            float4 a1 = *(const float4*)(attn2 + g8 * 8 + 4);
            float av[8] = {a0.x, a0.y, a0.z, a0.w, a1.x, a1.y, a1.z, a1.w};
#pragma unroll
            for (int e = 0; e < 8; ++e) {
                float v = (float)vs[e] + (float)vd[e];
                v = v > 0.0f ? v : 0.2f * v;
                acc += v * av[e];
            }
        }
        sal[tid] = acc;
    }
    __syncthreads();
    if (tid < 16) {
        int i = tid;
        float m = -1e30f;
#pragma unroll
        for (int j = 0; j < 16; ++j)
            if (j != i) m = fmaxf(m, sal[i * 16 + j]);
        float ex[16], den = 0.0f;
#pragma unroll
        for (int j = 0; j < 16; ++j) {
            ex[j] = (j == i) ? 0.0f : __expf(sal[i * 16 + j] - m);
            den += ex[j];
        }
        float rd = 1.0f / den;
#pragma unroll
        for (int j = 0; j < 16; ++j) sal[i * 16 + j] = ex[j] * rd;
    }
    __syncthreads();
    if (tid < 16) {
        float a = 0.0f;
#pragma unroll
        for (int i = 0; i < 16; ++i) a += sal[i * 16 + tid];
        wj[tid] = a * (1.0f / 16.0f);
    }
    __syncthreads();
    {
        int g = tid;
        float acc = 0.0f;
#pragma unroll
        for (int j = 0; j < 16; ++j) acc += wj[j] * (float)sb[j * 256 + g];
        ac_ws[b * 256 + g] = acc;
        out[(size_t)b * 259 + g] = acc;
    }
    if (tid < 2) out[(size_t)b * 259 + 256 + tid] = hideout[b * 2 + tid];
    if (tid == 0) out[(size_t)b * 259 + 258] = timestep[b];
}

// ---------------------------------------------------------------------------
// 5. CPC: one WG per t. pred/proj -> l2norm -> logits -> log-softmax diag.
// ---------------------------------------------------------------------------
__global__ __launch_bounds__(256, 1) void cpc_kernel(
    const float* __restrict__ ac,      // (128,256) f32
    const float* __restrict__ future,  // (128,12,2) f32
    const float* __restrict__ Wk,      // (12,16,256) f32
    const float* __restrict__ bk,      // (12,16) f32
    const float* __restrict__ Wl,      // (16,2) f32
    const float* __restrict__ bl,      // (16) f32
    float* __restrict__ loss_part)     // (12) f32
{
    __shared__ float pred[128][17];
    __shared__ float proj[128][17];
    __shared__ float red[4];
    const int tid = threadIdx.x, t = blockIdx.x;

    for (int ii = 0; ii < 8; ++ii) {
        int idx = tid + ii * 256;
        int b = idx >> 4, l = idx & 15;
        const float* wrow = Wk + ((size_t)t * 16 + l) * 256;
        const float* arow = ac + b * 256;
        float acc = bk[t * 16 + l];
        for (int g = 0; g < 256; g += 4) {
            float4 w = *(const float4*)(wrow + g);
            float4 a = *(const float4*)(arow + g);
            acc += w.x * a.x + w.y * a.y + w.z * a.z + w.w * a.w;
        }
        pred[b][l] = acc;
        float f0 = future[(b * 12 + t) * 2 + 0];
        float f1 = future[(b * 12 + t) * 2 + 1];
        proj[b][l] = f0 * Wl[l * 2 + 0] + f1 * Wl[l * 2 + 1] + bl[l];
    }
    __syncthreads();
    {
        float* row = (tid < 128) ? pred[tid] : proj[tid - 128];
        float ss = 0.0f;
#pragma unroll
        for (int l = 0; l < 16; ++l) ss += row[l] * row[l];
        float inv = 1.0f / fmaxf(sqrtf(ss), 1e-12f);
#pragma unroll
        for (int l = 0; l < 16; ++l) row[l] *= inv;
    }
    __syncthreads();
    float lsbb = 0.0f;
    if (tid < 128) {
        int b = tid;
        float tf[16];
#pragma unroll
        for (int l = 0; l < 16; ++l) tf[l] = proj[b][l];
        float mx = -1e30f, dbb = 0.0f;
        for (int cc = 0; cc < 128; ++cc) {
            float d = 0.0f;
#pragma unroll
            for (int l = 0; l < 16; ++l) d += tf[l] * pred[cc][l];
            mx = fmaxf(mx, d);
            if (cc == b) dbb = d;
        }
        float den = 0.0f;
        for (int cc = 0; cc < 128; ++cc) {
            float d = 0.0f;
#pragma unroll
            for (int l = 0; l < 16; ++l) d += tf[l] * pred[cc][l];
            den += __expf(d - mx);
        }
        lsbb = dbb - mx - __logf(den);
    }
#pragma unroll
    for (int o = 32; o > 0; o >>= 1) lsbb += __shfl_down(lsbb, o);
    if ((tid & 63) == 0) red[tid >> 6] = lsbb;
    __syncthreads();
    if (tid == 0) loss_part[t] = red[0] + red[1] + red[2] + red[3];
}

__global__ void final_kernel(const float* __restrict__ loss_part,
                             float* __restrict__ out)
{
    if (threadIdx.x == 0) {
        float s = 0.0f;
        for (int t = 0; t < 12; ++t) s += loss_part[t];
        out[33152] = -s / 1536.0f;
    }
}

// ---------------------------------------------------------------------------
extern "C" void kernel_launch(void* const* d_in, const int* in_sizes, int n_in,
                              void* d_out, int out_size, void* d_ws, size_t ws_size,
                              hipStream_t stream)
{
    const float* agent_obs = (const float*)d_in[0];
    const float* future    = (const float*)d_in[1];
    const float* hideout   = (const float*)d_in[2];
    const float* timestep  = (const float*)d_in[3];
    // d_in[4] = num_agents (int, ==16)
    const float* W_ih  = (const float*)d_in[5];
    const float* W_hh  = (const float*)d_in[6];
    const float* b_ih  = (const float*)d_in[7];
    const float* b_hh  = (const float*)d_in[8];
    const float* Wsrc1 = (const float*)d_in[9];
    const float* bsrc1 = (const float*)d_in[10];
    const float* Wdst1 = (const float*)d_in[11];
    const float* bdst1 = (const float*)d_in[12];
    const float* attn1 = (const float*)d_in[13];
    const float* Wsrc2 = (const float*)d_in[14];
    const float* bsrc2 = (const float*)d_in[15];
    const float* Wdst2 = (const float*)d_in[16];
    const float* bdst2 = (const float*)d_in[17];
    const float* attn2 = (const float*)d_in[18];
    const float* Wk    = (const float*)d_in[19];
    const float* bk    = (const float*)d_in[20];
    const float* Wl    = (const float*)d_in[21];
    const float* bl    = (const float*)d_in[22];
    float* out = (float*)d_out;

    char* ws = (char*)d_ws;
    const size_t KB = 1024;
    bf16*  wihb  = (bf16*)(ws);                  // 32 KB  (1024x16)
    bf16*  whh2  = (bf16*)(ws + 32 * KB);        // 512 KB (16,512,32) chunked
    bf16*  ws1b  = (bf16*)(ws + 544 * KB);       // 1 MB   (2048x256)
    bf16*  wd1b  = (bf16*)(ws + 1568 * KB);      // 1 MB
    bf16*  ws2b  = (bf16*)(ws + 2592 * KB);      // 128 KB (256x256)
    bf16*  wd2b  = (bf16*)(ws + 2720 * KB);      // 128 KB
    bf16*  hn    = (bf16*)(ws + 2848 * KB);      // 1 MB   (2048x256)
    bf16*  src1  = (bf16*)(ws + 3872 * KB);      // 8 MB   (2048x2048)
    bf16*  dst1  = (bf16*)(ws + 12064 * KB);     // 8 MB
    bf16*  r1    = (bf16*)(ws + 20256 * KB);     // 1 MB   (2048x256)
    bf16*  src2  = (bf16*)(ws + 21280 * KB);     // 1 MB
    bf16*  dst2  = (bf16*)(ws + 22304 * KB);     // 1 MB
    float* acf   = (float*)(ws + 23328 * KB);    // 128 KB (128x256 f32)
    float* lossp = (float*)(ws + 23456 * KB);    // 48 B

    cvt6<<<1424, 256, 0, stream>>>(W_ih, W_hh, Wsrc1, Wdst1, Wsrc2, Wdst2,
                                   wihb, whh2, ws1b, wd1b, ws2b, wd2b);
    lstm_kernel<<<128, 1024, 0, stream>>>(agent_obs, wihb, whh2, b_ih, b_hh, hn);
    gemm_bias<<<dim3(32, 32), 256, 0, stream>>>(hn, ws1b, bsrc1, src1, 2048, 2048);
    gemm_bias<<<dim3(32, 32), 256, 0, stream>>>(hn, wd1b, bdst1, dst1, 2048, 2048);
    gat1_kernel<<<128, 256, 0, stream>>>(src1, dst1, attn1, r1);
    gemm_bias<<<dim3(4, 32), 256, 0, stream>>>(r1, ws2b, bsrc2, src2, 2048, 256);
    gemm_bias<<<dim3(4, 32), 256, 0, stream>>>(r1, wd2b, bdst2, dst2, 2048, 256);
    gat2_kernel<<<128, 256, 0, stream>>>(src2, dst2, attn2, hideout, timestep, out, acf);
    cpc_kernel<<<12, 256, 0, stream>>>(acf, future, Wk, bk, Wl, bl, lossp);
    final_kernel<<<1, 64, 0, stream>>>(lossp, out);
}

// Round 6
// 1491.415 us; speedup vs baseline: 3.1489x; 1.1576x over previous
//
#include <hip/hip_runtime.h>

// CPCGNN: LSTM(2048 x 128 steps, F=16, H=256) -> GATv2 x2 (16-node graphs) ->
// mean pool -> CPC loss. Inputs/outputs FLOAT32; MFMA paths use bf16 copies.
//
// Round 6: LSTM = 128 WGs x 1024 threads (16 waves, 4/SIMD pinned via
// amdgpu_waves_per_eu(4,4) -> 128-VGPR budget, no spill). Wave w owns tau=w.
// W_hh read directly global->VGPR from chunk-major whh2 (contiguous 1KB per
// wave-instruction), rolled kc loop w/ unroll 2, h double-buffered in LDS,
// one barrier/step. x-MFMA deferred to after the K loop to hide its load.

typedef __bf16 bf16;
typedef bf16 bf16x4 __attribute__((ext_vector_type(4)));
typedef bf16 bf16x8 __attribute__((ext_vector_type(8)));
typedef float f32x4 __attribute__((ext_vector_type(4)));

__device__ __forceinline__ float fast_sigmoid(float x) {
    return __builtin_amdgcn_rcpf(1.0f + __expf(-x));
}
__device__ __forceinline__ float fast_tanh(float x) {
    return 2.0f * __builtin_amdgcn_rcpf(1.0f + __expf(-2.0f * x)) - 1.0f;
}
__device__ __forceinline__ bf16x8 zero8() {
    bf16x8 z;
#pragma unroll
    for (int i = 0; i < 8; ++i) z[i] = (bf16)0.0f;
    return z;
}
__device__ __forceinline__ bf16x8 load8_bf(const float* p) {
    float4 a = *(const float4*)p;
    float4 b = *(const float4*)(p + 4);
    bf16x8 r;
    r[0] = (bf16)a.x; r[1] = (bf16)a.y; r[2] = (bf16)a.z; r[3] = (bf16)a.w;
    r[4] = (bf16)b.x; r[5] = (bf16)b.y; r[6] = (bf16)b.z; r[7] = (bf16)b.w;
    return r;
}

// ---------------------------------------------------------------------------
// 0. Weight f32 -> bf16. W_hh chunk-major: chunk ic = (k>>5)*2 + (n>>9) holds
//    rows (n&511) x k-slice (k&31), layout whh2[16][512][32].
// ---------------------------------------------------------------------------
__global__ __launch_bounds__(256, 1) void cvt6(
    const float* __restrict__ s0, const float* __restrict__ s1,
    const float* __restrict__ s2, const float* __restrict__ s3,
    const float* __restrict__ s4, const float* __restrict__ s5,
    bf16* __restrict__ d0, bf16* __restrict__ d1, bf16* __restrict__ d2,
    bf16* __restrict__ d3, bf16* __restrict__ d4, bf16* __restrict__ d5)
{
    const int n0 = 16384, n1 = 262144, n2 = 524288, n3 = 524288, n4 = 65536;
    int loc = (blockIdx.x * 256 + threadIdx.x) * 4;
    const float* s; bf16* d; int dst;
    if (loc < n0)              { s = s0; d = d0; dst = loc; }
    else if ((loc -= n0) < n1) {
        s = s1; d = d1;
        int n = loc >> 8, k = loc & 255;
        dst = ((((k >> 5) << 1) | (n >> 9)) << 14) + ((n & 511) << 5) + (k & 31);
    }
    else if ((loc -= n1) < n2) { s = s2; d = d2; dst = loc; }
    else if ((loc -= n2) < n3) { s = s3; d = d3; dst = loc; }
    else if ((loc -= n3) < n4) { s = s4; d = d4; dst = loc; }
    else                       { loc -= n4; s = s5; d = d5; dst = loc; }
    float4 v = *(const float4*)(s + loc);
    bf16x4 o;
    o[0] = (bf16)v.x; o[1] = (bf16)v.y; o[2] = (bf16)v.z; o[3] = (bf16)v.w;
    *(bf16x4*)(d + dst) = o;
}

// ---------------------------------------------------------------------------
// 1. LSTM. WG b = graph b (16 rows). 16 waves; wave w owns tau=w: gate-cols
//    n = G*256 + w*16 + col for G=0..3. Per step per wave: 32 direct 16B
//    W loads (rolled kc loop, unroll 2), 36 MFMA, gates, 1 barrier.
// ---------------------------------------------------------------------------
__global__ __launch_bounds__(1024)
__attribute__((amdgpu_waves_per_eu(4, 4)))
void lstm_kernel(
    const float* __restrict__ agent_obs,  // (128,128,16,16) f32
    const bf16* __restrict__ W_ih,        // (1024,16) bf16
    const bf16* __restrict__ whh2,        // (16,512,32) bf16 chunk-major
    const float* __restrict__ b_ih,
    const float* __restrict__ b_hh,
    bf16* __restrict__ hn)                // (2048,256) bf16
{
    __shared__ bf16 hbuf[2][16][264];     // +8 pad; double-buffered h
    const int tid  = threadIdx.x;
    const int lane = tid & 63;
    const int w    = tid >> 6;            // wave id = tau
    const int col  = lane & 15;           // A-row (agent) / B-col (within tau)
    const int grp  = lane >> 4;           // k-group
    const int b    = blockIdx.x;

    for (int i = tid; i < 2 * 16 * 264; i += 1024) (&hbuf[0][0][0])[i] = (bf16)0.0f;

    // per-lane invariants
    float bias[4];
    bf16x8 wih[4];
    const bf16* wp[4];                    // &whh2[chunk(G,kc=0)][r512][grp*8]
#pragma unroll
    for (int G = 0; G < 4; ++G) {
        int n = G * 256 + w * 16 + col;
        bias[G] = b_ih[n] + b_hh[n];
        wih[G] = (grp < 2) ? *(const bf16x8*)&W_ih[n * 16 + grp * 8] : zero8();
        wp[G] = whh2 + (G >> 1) * 16384 + (n & 511) * 32 + grp * 8;
    }
    f32x4 c = (f32x4){0.0f, 0.0f, 0.0f, 0.0f};

    const float* xb = agent_obs + (size_t)b * 32768;

    __syncthreads();

    for (int s = 0; s < 128; ++s) {
        const int pr = s & 1, pw = pr ^ 1;
        // issue x load early; consumed only after the K loop (latency hidden)
        bf16x8 ax = (grp < 2) ? load8_bf(xb + s * 256 + col * 16 + grp * 8)
                              : zero8();
        f32x4 acc[4];
#pragma unroll
        for (int G = 0; G < 4; ++G) {
            float bs_ = bias[G];
            acc[G] = (f32x4){bs_, bs_, bs_, bs_};
        }
        // recurrent K loop: h @ W_hh^T (W from L2, 1KB contiguous per instr)
#pragma unroll 2
        for (int kc = 0; kc < 8; ++kc) {
            bf16x8 bw0 = *(const bf16x8*)(wp[0] + kc * 32768);
            bf16x8 bw1 = *(const bf16x8*)(wp[1] + kc * 32768);
            bf16x8 bw2 = *(const bf16x8*)(wp[2] + kc * 32768);
            bf16x8 bw3 = *(const bf16x8*)(wp[3] + kc * 32768);
            bf16x8 ah = *(const bf16x8*)&hbuf[pr][col][kc * 32 + grp * 8];
            acc[0] = __builtin_amdgcn_mfma_f32_16x16x32_bf16(ah, bw0, acc[0], 0, 0, 0);
            acc[1] = __builtin_amdgcn_mfma_f32_16x16x32_bf16(ah, bw1, acc[1], 0, 0, 0);
            acc[2] = __builtin_amdgcn_mfma_f32_16x16x32_bf16(ah, bw2, acc[2], 0, 0, 0);
            acc[3] = __builtin_amdgcn_mfma_f32_16x16x32_bf16(ah, bw3, acc[3], 0, 0, 0);
        }
        // input contribution (ax long since arrived)
#pragma unroll
        for (int G = 0; G < 4; ++G)
            acc[G] = __builtin_amdgcn_mfma_f32_16x16x32_bf16(ax, wih[G], acc[G], 0, 0, 0);
        // gates: lane holds rows m=grp*4+r, col j=w*16+col
#pragma unroll
        for (int r = 0; r < 4; ++r) {
            float iv = fast_sigmoid(acc[0][r]);
            float fv = fast_sigmoid(acc[1][r]);
            float gv = fast_tanh(acc[2][r]);
            float ov = fast_sigmoid(acc[3][r]);
            float cn = fv * c[r] + iv * gv;
            c[r] = cn;
            float hv = ov * fast_tanh(cn);
            int m = grp * 4 + r, j = w * 16 + col;
            if (s == 127) hn[((size_t)b * 16 + m) * 256 + j] = (bf16)hv;
            else          hbuf[pw][m][j] = (bf16)hv;
        }
        __syncthreads();
    }
}

// ---------------------------------------------------------------------------
// 2. GEMM: C[M,N] = A[M,256] @ W[N,256]^T + bias. A,W,C bf16; bias f32.
// ---------------------------------------------------------------------------
__global__ __launch_bounds__(256, 1) void gemm_bias(
    const bf16* __restrict__ A, const bf16* __restrict__ W,
    const float* __restrict__ bias, bf16* __restrict__ C, int M, int N)
{
    const int tid = threadIdx.x, lane = tid & 63, wv = tid >> 6;
    const int col = lane & 15, grp = lane >> 4;
    const int n = blockIdx.x * 64 + wv * 16 + col;
    const int bm = blockIdx.y * 64;
    float bs = bias[n];
    f32x4 acc[4];
#pragma unroll
    for (int mt = 0; mt < 4; ++mt) acc[mt] = (f32x4){bs, bs, bs, bs};
#pragma unroll
    for (int kc = 0; kc < 8; ++kc) {
        bf16x8 bw = *(const bf16x8*)&W[(size_t)n * 256 + kc * 32 + grp * 8];
#pragma unroll
        for (int mt = 0; mt < 4; ++mt) {
            bf16x8 aa = *(const bf16x8*)
                &A[(size_t)(bm + mt * 16 + col) * 256 + kc * 32 + grp * 8];
            acc[mt] = __builtin_amdgcn_mfma_f32_16x16x32_bf16(aa, bw, acc[mt], 0, 0, 0);
        }
    }
#pragma unroll
    for (int mt = 0; mt < 4; ++mt)
#pragma unroll
        for (int r = 0; r < 4; ++r)
            C[(size_t)(bm + mt * 16 + grp * 4 + r) * N + n] = (bf16)acc[mt][r];
}

// ---------------------------------------------------------------------------
// 3. GATv2 layer 1: scores + edge softmax (no self) + head-mean aggregation.
// ---------------------------------------------------------------------------
__global__ __launch_bounds__(256, 1) void gat1_kernel(
    const bf16* __restrict__ src,    // (2048, 2048) = (b*16+n, h*256+f)
    const bf16* __restrict__ dst,
    const float* __restrict__ attn,  // (8,256) f32
    bf16* __restrict__ r1)           // (2048, 256)
{
    __shared__ float sal[2048];      // (i*16+j)*8+h
    const int tid = threadIdx.x, b = blockIdx.x;
    const bf16* sb = src + (size_t)b * 32768;
    const bf16* db = dst + (size_t)b * 32768;

    for (int ii = 0; ii < 8; ++ii) {
        int trip = tid + ii * 256;            // i*128 + j*8 + h
        int i = trip >> 7, j = (trip >> 3) & 15, h = trip & 7;
        const bf16* ps = sb + j * 2048 + h * 256;
        const bf16* pd = db + i * 2048 + h * 256;
        const float* pa = attn + h * 256;
        float acc = 0.0f;
        for (int f8 = 0; f8 < 32; ++f8) {
            bf16x8 vs = *(const bf16x8*)(ps + f8 * 8);
            bf16x8 vd = *(const bf16x8*)(pd + f8 * 8);
            float4 a0 = *(const float4*)(pa + f8 * 8);
            float4 a1 = *(const float4*)(pa + f8 * 8 + 4);
            float av[8] = {a0.x, a0.y, a0.z, a0.w, a1.x, a1.y, a1.z, a1.w};
#pragma unroll
            for (int e = 0; e < 8; ++e) {
                float v = (float)vs[e] + (float)vd[e];
                v = v > 0.0f ? v : 0.2f * v;
                acc += v * av[e];
            }
        }
        sal[trip] = acc;
    }
    __syncthreads();
    if (tid < 128) {                          // softmax over j != i
        int i = tid >> 3, h = tid & 7;
        float m = -1e30f;
#pragma unroll
        for (int j = 0; j < 16; ++j)
            if (j != i) m = fmaxf(m, sal[(i * 16 + j) * 8 + h]);
        float ex[16], den = 0.0f;
#pragma unroll
        for (int j = 0; j < 16; ++j) {
            ex[j] = (j == i) ? 0.0f : __expf(sal[(i * 16 + j) * 8 + h] - m);
            den += ex[j];
        }
        float rd = 1.0f / den;
#pragma unroll
        for (int j = 0; j < 16; ++j) sal[(i * 16 + j) * 8 + h] = ex[j] * rd;
    }
    __syncthreads();
    {
        int i = tid >> 4, fb = tid & 15;
        for (int it = 0; it < 16; ++it) {
            int f = fb + it * 16;
            float acc = 0.0f;
            for (int j = 0; j < 16; ++j) {
                const bf16* ps = sb + j * 2048 + f;
#pragma unroll
                for (int h = 0; h < 8; ++h)
                    acc += sal[(i * 16 + j) * 8 + h] * (float)ps[h * 256];
            }
            r1[((size_t)b * 16 + i) * 256 + f] = (bf16)(acc * 0.125f);
        }
    }
}

// ---------------------------------------------------------------------------
// 4. GATv2 layer 2 (1 head) fused with node-mean + d_out row writes.
// ---------------------------------------------------------------------------
__global__ __launch_bounds__(256, 1) void gat2_kernel(
    const bf16* __restrict__ src2,   // (2048,256)
    const bf16* __restrict__ dst2,
    const float* __restrict__ attn2, // (256) f32
    const float* __restrict__ hideout,   // (128,2) f32
    const float* __restrict__ timestep,  // (128,1) f32
    float* __restrict__ out,             // (128,259)+loss f32
    float* __restrict__ ac_ws)           // (128,256) f32
{
    __shared__ float sal[256];
    __shared__ float wj[16];
    const int tid = threadIdx.x, b = blockIdx.x;
    const bf16* sb = src2 + (size_t)b * 4096;
    const bf16* db = dst2 + (size_t)b * 4096;
    {
        int i = tid >> 4, j = tid & 15;
        const bf16* ps = sb + j * 256;
        const bf16* pd = db + i * 256;
        float acc = 0.0f;
        for (int g8 = 0; g8 < 32; ++g8) {
            bf16x8 vs = *(const bf16x8*)(ps + g8 * 8);
            bf16x8 vd = *(const bf16x8*)(pd + g8 * 8);
            float4 a0 = *(const float4*)(attn2 + g8 * 8);
            float4 a1 = *(const float4*)(attn2 + g8 * 8 + 4);
            float av[8] = {a0.x, a0.y, a0.z, a0.w, a1.x, a1.y, a1.z, a1.w};
#pragma unroll
            for (int e = 0; e < 8; ++e) {
                float v = (float)vs[e] + (float)vd[e];
                v = v > 0.0f ? v : 0.2f * v;
                acc += v * av[e];
            }
        }
        sal[tid] = acc;
    }
    __syncthreads();
    if (tid < 16) {
        int i = tid;
        float m = -1e30f;
#pragma unroll
        for (int j = 0; j < 16; ++j)
            if (j != i) m = fmaxf(m, sal[i * 16 + j]);
        float ex[16], den = 0.0f;
#pragma unroll
        for (int j = 0; j < 16; ++j) {
            ex[j] = (j == i) ? 0.0f : __expf(sal[i * 16 + j] - m);
            den += ex[j];
        }
        float rd = 1.0f / den;
#pragma unroll
        for (int j = 0; j < 16; ++j) sal[i * 16 + j] = ex[j] * rd;
    }
    __syncthreads();
    if (tid < 16) {
        float a = 0.0f;
#pragma unroll
        for (int i = 0; i < 16; ++i) a += sal[i * 16 + tid];
        wj[tid] = a * (1.0f / 16.0f);
    }
    __syncthreads();
    {
        int g = tid;
        float acc = 0.0f;
#pragma unroll
        for (int j = 0; j < 16; ++j) acc += wj[j] * (float)sb[j * 256 + g];
        ac_ws[b * 256 + g] = acc;
        out[(size_t)b * 259 + g] = acc;
    }
    if (tid < 2) out[(size_t)b * 259 + 256 + tid] = hideout[b * 2 + tid];
    if (tid == 0) out[(size_t)b * 259 + 258] = timestep[b];
}

// ---------------------------------------------------------------------------
// 5. CPC: one WG per t. pred/proj -> l2norm -> logits -> log-softmax diag.
// ---------------------------------------------------------------------------
__global__ __launch_bounds__(256, 1) void cpc_kernel(
    const float* __restrict__ ac,      // (128,256) f32
    const float* __restrict__ future,  // (128,12,2) f32
    const float* __restrict__ Wk,      // (12,16,256) f32
    const float* __restrict__ bk,      // (12,16) f32
    const float* __restrict__ Wl,      // (16,2) f32
    const float* __restrict__ bl,      // (16) f32
    float* __restrict__ loss_part)     // (12) f32
{
    __shared__ float pred[128][17];
    __shared__ float proj[128][17];
    __shared__ float red[4];
    const int tid = threadIdx.x, t = blockIdx.x;

    for (int ii = 0; ii < 8; ++ii) {
        int idx = tid + ii * 256;
        int b = idx >> 4, l = idx & 15;
        const float* wrow = Wk + ((size_t)t * 16 + l) * 256;
        const float* arow = ac + b * 256;
        float acc = bk[t * 16 + l];
        for (int g = 0; g < 256; g += 4) {
            float4 w = *(const float4*)(wrow + g);
            float4 a = *(const float4*)(arow + g);
            acc += w.x * a.x + w.y * a.y + w.z * a.z + w.w * a.w;
        }
        pred[b][l] = acc;
        float f0 = future[(b * 12 + t) * 2 + 0];
        float f1 = future[(b * 12 + t) * 2 + 1];
        proj[b][l] = f0 * Wl[l * 2 + 0] + f1 * Wl[l * 2 + 1] + bl[l];
    }
    __syncthreads();
    {
        float* row = (tid < 128) ? pred[tid] : proj[tid - 128];
        float ss = 0.0f;
#pragma unroll
        for (int l = 0; l < 16; ++l) ss += row[l] * row[l];
        float inv = 1.0f / fmaxf(sqrtf(ss), 1e-12f);
#pragma unroll
        for (int l = 0; l < 16; ++l) row[l] *= inv;
    }
    __syncthreads();
    float lsbb = 0.0f;
    if (tid < 128) {
        int b = tid;
        float tf[16];
#pragma unroll
        for (int l = 0; l < 16; ++l) tf[l] = proj[b][l];
        float mx = -1e30f, dbb = 0.0f;
        for (int cc = 0; cc < 128; ++cc) {
            float d = 0.0f;
#pragma unroll
            for (int l = 0; l < 16; ++l) d += tf[l] * pred[cc][l];
            mx = fmaxf(mx, d);
            if (cc == b) dbb = d;
        }
        float den = 0.0f;
        for (int cc = 0; cc < 128; ++cc) {
            float d = 0.0f;
#pragma unroll
            for (int l = 0; l < 16; ++l) d += tf[l] * pred[cc][l];
            den += __expf(d - mx);
        }
        lsbb = dbb - mx - __logf(den);
    }
#pragma unroll
    for (int o = 32; o > 0; o >>= 1) lsbb += __shfl_down(lsbb, o);
    if ((tid & 63) == 0) red[tid >> 6] = lsbb;
    __syncthreads();
    if (tid == 0) loss_part[t] = red[0] + red[1] + red[2] + red[3];
}

__global__ void final_kernel(const float* __restrict__ loss_part,
                             float* __restrict__ out)
{
    if (threadIdx.x == 0) {
        float s = 0.0f;
        for (int t = 0; t < 12; ++t) s += loss_part[t];
        out[33152] = -s / 1536.0f;
    }
}

// ---------------------------------------------------------------------------
extern "C" void kernel_launch(void* const* d_in, const int* in_sizes, int n_in,
                              void* d_out, int out_size, void* d_ws, size_t ws_size,
                              hipStream_t stream)
{
    const float* agent_obs = (const float*)d_in[0];
    const float* future    = (const float*)d_in[1];
    const float* hideout   = (const float*)d_in[2];
    const float* timestep  = (const float*)d_in[3];
    // d_in[4] = num_agents (int, ==16)
    const float* W_ih  = (const float*)d_in[5];
    const float* W_hh  = (const float*)d_in[6];
    const float* b_ih  = (const float*)d_in[7];
    const float* b_hh  = (const float*)d_in[8];
    const float* Wsrc1 = (const float*)d_in[9];
    const float* bsrc1 = (const float*)d_in[10];
    const float* Wdst1 = (const float*)d_in[11];
    const float* bdst1 = (const float*)d_in[12];
    const float* attn1 = (const float*)d_in[13];
    const float* Wsrc2 = (const float*)d_in[14];
    const float* bsrc2 = (const float*)d_in[15];
    const float* Wdst2 = (const float*)d_in[16];
    const float* bdst2 = (const float*)d_in[17];
    const float* attn2 = (const float*)d_in[18];
    const float* Wk    = (const float*)d_in[19];
    const float* bk    = (const float*)d_in[20];
    const float* Wl    = (const float*)d_in[21];
    const float* bl    = (const float*)d_in[22];
    float* out = (float*)d_out;

    char* ws = (char*)d_ws;
    const size_t KB = 1024;
    bf16*  wihb  = (bf16*)(ws);                  // 32 KB  (1024x16)
    bf16*  whh2  = (bf16*)(ws + 32 * KB);        // 512 KB (16,512,32) chunked
    bf16*  ws1b  = (bf16*)(ws + 544 * KB);       // 1 MB   (2048x256)
    bf16*  wd1b  = (bf16*)(ws + 1568 * KB);      // 1 MB
    bf16*  ws2b  = (bf16*)(ws + 2592 * KB);      // 128 KB (256x256)
    bf16*  wd2b  = (bf16*)(ws + 2720 * KB);      // 128 KB
    bf16*  hn    = (bf16*)(ws + 2848 * KB);      // 1 MB   (2048x256)
    bf16*  src1  = (bf16*)(ws + 3872 * KB);      // 8 MB   (2048x2048)
    bf16*  dst1  = (bf16*)(ws + 12064 * KB);     // 8 MB
    bf16*  r1    = (bf16*)(ws + 20256 * KB);     // 1 MB   (2048x256)
    bf16*  src2  = (bf16*)(ws + 21280 * KB);     // 1 MB
    bf16*  dst2  = (bf16*)(ws + 22304 * KB);     // 1 MB
    float* acf   = (float*)(ws + 23328 * KB);    // 128 KB (128x256 f32)
    float* lossp = (float*)(ws + 23456 * KB);    // 48 B

    cvt6<<<1424, 256, 0, stream>>>(W_ih, W_hh, Wsrc1, Wdst1, Wsrc2, Wdst2,
                                   wihb, whh2, ws1b, wd1b, ws2b, wd2b);
    lstm_kernel<<<128, 1024, 0, stream>>>(agent_obs, wihb, whh2, b_ih, b_hh, hn);
    gemm_bias<<<dim3(32, 32), 256, 0, stream>>>(hn, ws1b, bsrc1, src1, 2048, 2048);
    gemm_bias<<<dim3(32, 32), 256, 0, stream>>>(hn, wd1b, bdst1, dst1, 2048, 2048);
    gat1_kernel<<<128, 256, 0, stream>>>(src1, dst1, attn1, r1);
    gemm_bias<<<dim3(4, 32), 256, 0, stream>>>(r1, ws2b, bsrc2, src2, 2048, 256);
    gemm_bias<<<dim3(4, 32), 256, 0, stream>>>(r1, wd2b, bdst2, dst2, 2048, 256);
    gat2_kernel<<<128, 256, 0, stream>>>(src2, dst2, attn2, hideout, timestep, out, acf);
    cpc_kernel<<<12, 256, 0, stream>>>(acf, future, Wk, bk, Wl, bl, lossp);
    final_kernel<<<1, 64, 0, stream>>>(lossp, out);
}